// Round 3
// baseline (576.733 us; speedup 1.0000x reference)
//
#include <hip/hip_runtime.h>

#define H 80
#define W 80
#define DD 20
#define C 32
#define NPOS (H*W)          // 6400
#define NP3 (NPOS*DD)       // 128000
#define SO 9
#define DO_ 5
#define NDISP (DO_*SO*SO)   // 405

#define NC 8                // channels staged per chunk
#define NCHUNK (C/NC)       // 4
#define XQ 20               // x-positions per block
#define COLS 28             // XQ + 8 halo columns
#define ZST 28              // z stride: 2 front pad + 20 real + 6 back pad (16B-mult)
#define CHUNK_FLOATS (NC*COLS*ZST)   // 6272 floats = 24.5 KB per buffer

typedef float nt4 __attribute__((ext_vector_type(4)));   // native vec for NT stores

// Fused cost-volume + mask kernel, double-buffered LDS staging.
// block = (y, di, x-quarter); threads = (djg:3, xl:20, zg:5) = 300 active / 320.
// Chunk c+1 is staged into buf[(c+1)&1] while chunk c computes from buf[c&1]:
// one barrier per chunk (6 total vs 17 single-buffered).
// Outputs stored non-temporally so the 415 MB stream doesn't evict the 33 MB
// f1/f2 L2 working set (f1 is re-read 27x logically).
// Accumulation order (c ascending, fmaf, *1/32 at end) is bit-identical to the
// previous passing kernel (absmax 0.0).
__global__ __launch_bounds__(320, 4)
void fused_kernel(const float* __restrict__ f1, const float* __restrict__ a1,
                  const float* __restrict__ f2, const float* __restrict__ a2,
                  float* __restrict__ outc, float* __restrict__ outm)
{
    __shared__ __align__(16) float f2s[2][CHUNK_FLOATS];   // 50176 B
    __shared__ float m1s[XQ];
    __shared__ float m2s[COLS];

    // XCD-aware swizzle: 2880 blocks % 8 == 0 -> 360 contiguous per XCD;
    // consecutive-per-XCD blocks share y -> f1/f2 rows stay L2-local.
    int bid = blockIdx.x;
    int swz = (bid & 7) * 360 + (bid >> 3);
    int y  = swz / 36;
    int r0 = swz % 36;
    int di = r0 >> 2;       // 0..8
    int xq = r0 & 3;        // 0..3

    int t   = threadIdx.x;
    int djg = t / 100;      // 0..2 (active threads)
    int r   = t % 100;
    int xl  = r / 5;        // 0..19
    int zg  = r % 5;        // 0..4
    int z0  = zg * 4;
    int x   = xq * XQ + xl;
    int pos = y * W + x;
    int y2  = y + di - 4;
    bool y2ok = ((unsigned)y2 < (unsigned)H);
    bool act  = (t < 300);

    // staging role: threads [96,320) -> 224 = NC*COLS stagers
    int s    = t - 96;
    int sc_  = s / COLS;          // channel within chunk 0..7
    int scol = s % COLS;          // halo column 0..27
    int sx2  = xq * XQ + scol - 4;
    bool stager = (t >= 96) && y2ok && ((unsigned)sx2 < (unsigned)W);
    const float* sp_base = stager ? (f2 + (size_t)sc_ * NP3 + (y2 * W + sx2) * DD) : f2;
    float* sd = &f2s[0][0] + (sc_ * COLS + scol) * ZST + 2;   // +2: front depth pad

    // One-time zero of both buffers: covers depth pads, OOR halo columns, and
    // fully-OOR rows (y2ok == false). Staging never writes the pad area.
    for (int i = t; i < 2 * CHUNK_FLOATS / 4; i += 320)
        ((float4*)f2s)[i] = make_float4(0.f, 0.f, 0.f, 0.f);

    // visibility row-sums (same arithmetic order as the passing kernel)
    if (t < XQ){
        const float* p = a1 + (y * W + xq * XQ + t) * DD;
        float sm = 0.f;
        #pragma unroll
        for (int q = 0; q < 5; ++q){
            float4 v = *(const float4*)(p + q * 4);
            sm += v.x + v.y + v.z + v.w;
        }
        m1s[t] = fminf(fmaxf(sm, 0.f), 1.f);
    } else if (t >= 32 && t < 32 + COLS){
        int col = t - 32;
        int x2 = xq * XQ + col - 4;
        float m = 1.f;                       // spatial/row pad of mask2 is 1.0
        if (y2ok && ((unsigned)x2 < (unsigned)W)){
            const float* p = a2 + (y2 * W + x2) * DD;
            float sm = 0.f;
            #pragma unroll
            for (int q = 0; q < 5; ++q){
                float4 v = *(const float4*)(p + q * 4);
                sm += v.x + v.y + v.z + v.w;
            }
            m = fminf(fmaxf(sm, 0.f), 1.f);
        }
        m2s[col] = m;
    }
    __syncthreads();          // zero-fill complete before staging writes

    // prologue: stage chunk 0 into buf 0
    if (stager){
        #pragma unroll
        for (int q = 0; q < 5; ++q){
            float4 v = *(const float4*)(sp_base + q * 4);
            *(float2*)(sd + q * 4)     = make_float2(v.x, v.y);
            *(float2*)(sd + q * 4 + 2) = make_float2(v.z, v.w);
        }
    }
    __syncthreads();

    float acc[3][DO_][4];
    #pragma unroll
    for (int i = 0; i < 3; ++i)
        #pragma unroll
        for (int j = 0; j < DO_; ++j)
            #pragma unroll
            for (int k = 0; k < 4; ++k) acc[i][j][k] = 0.f;

    const float* a_base = f1 + pos * DD + z0;

    #pragma unroll 1
    for (int cc = 0; cc < NCHUNK; ++cc){
        // ---- stage NEXT chunk into the other buffer (overlaps with compute) ----
        if (cc < NCHUNK - 1 && stager){
            const float* p = sp_base + (size_t)(cc + 1) * NC * NP3;
            float* d = sd + ((cc + 1) & 1) * CHUNK_FLOATS;
            #pragma unroll
            for (int q = 0; q < 5; ++q){
                float4 v = *(const float4*)(p + q * 4);
                *(float2*)(d + q * 4)     = make_float2(v.x, v.y);
                *(float2*)(d + q * 4 + 2) = make_float2(v.z, v.w);
            }
        }
        // ---- compute current chunk from buf[cc&1] ----
        if (act){
            const float* base = &f2s[cc & 1][0];
            #pragma unroll
            for (int c = 0; c < NC; ++c){
                float4 avv = *(const float4*)(a_base + (size_t)(cc * NC + c) * NP3);
                float av[4] = {avv.x, avv.y, avv.z, avv.w};
                #pragma unroll
                for (int djl = 0; djl < 3; ++djl){
                    int dj = djg * 3 + djl;
                    // window zs = z0 .. z0+7  <=>  zp = z0-2 .. z0+5 (16B aligned)
                    const float* bp = base + (c * COLS + xl + dj) * ZST + z0;
                    float4 b0 = *(const float4*)(bp);
                    float4 b1 = *(const float4*)(bp + 4);
                    float bb[8] = {b0.x, b0.y, b0.z, b0.w, b1.x, b1.y, b1.z, b1.w};
                    #pragma unroll
                    for (int dk = 0; dk < DO_; ++dk)
                        #pragma unroll
                        for (int z = 0; z < 4; ++z)
                            acc[djl][dk][z] = fmaf(av[z], bb[z + dk], acc[djl][dk][z]);
                }
            }
        }
        if (cc < NCHUNK - 1) __syncthreads();   // buf[(cc+1)&1] ready; readers of buf[cc&1] done
    }

    if (act){
        const float sc = 1.0f / 32.0f;
        float m1v = m1s[xl];
        #pragma unroll
        for (int djl = 0; djl < 3; ++djl){
            int dj = djg * 3 + djl;
            float m2v = m2s[xl + dj];            // 1.0 when spatially OOR -> mi == m1v
            float mi = fminf(m1v * m2v, 1.f);
            #pragma unroll
            for (int dk = 0; dk < DO_; ++dk){
                size_t off = (size_t)(dk * 81 + di * 9 + dj) * NP3 + pos * DD + z0;
                nt4 wv;
                wv.x = acc[djl][dk][0] * sc;
                wv.y = acc[djl][dk][1] * sc;
                wv.z = acc[djl][dk][2] * sc;
                wv.w = acc[djl][dk][3] * sc;
                __builtin_nontemporal_store(wv, (nt4*)(outc + off));
                int zlo = 2 - dk, zhi = 22 - dk;  // depth pad of mask2 = 1 -> m1v
                nt4 mv;
                mv.x = (z0 + 0 >= zlo && z0 + 0 < zhi) ? mi : m1v;
                mv.y = (z0 + 1 >= zlo && z0 + 1 < zhi) ? mi : m1v;
                mv.z = (z0 + 2 >= zlo && z0 + 2 < zhi) ? mi : m1v;
                mv.w = (z0 + 3 >= zlo && z0 + 3 < zhi) ? mi : m1v;
                __builtin_nontemporal_store(mv, (nt4*)(outm + off));
            }
        }
    }
}

extern "C" void kernel_launch(void* const* d_in, const int* in_sizes, int n_in,
                              void* d_out, int out_size, void* d_ws, size_t ws_size,
                              hipStream_t stream)
{
    const float* f1 = (const float*)d_in[0];   // mpi1_features [32][80][80][20] f32
    const float* a1 = (const float*)d_in[1];   // mpi1_alpha
    const float* f2 = (const float*)d_in[2];   // mpi2_features
    const float* a2 = (const float*)d_in[3];   // mpi2_alpha
    float* outc = (float*)d_out;                   // cost volume [405][6400][20]
    float* outm = outc + (size_t)NDISP * NP3;      // mask volume, same shape
    (void)d_ws; (void)ws_size; (void)in_sizes; (void)n_in;

    fused_kernel<<<80 * SO * 4, 320, 0, stream>>>(f1, a1, f2, a2, outc, outm);
}

// Round 4
// 557.908 us; speedup vs baseline: 1.0337x; 1.0337x over previous
//
#include <hip/hip_runtime.h>

#define H 80
#define W 80
#define DD 20
#define C 32
#define NPOS (H*W)          // 6400
#define NP3 (NPOS*DD)       // 128000
#define SO 9
#define DO_ 5
#define NDISP (DO_*SO*SO)   // 405

#define NC 4                // channels staged per chunk
#define NCHUNK (C/NC)       // 8
#define XQ 20               // x-positions per block
#define COLS 28             // XQ + 8 halo columns
#define ZST 28              // z stride: 2 front pad + 20 real + 6 back pad.
                            // 28 floats = 112 B: row stride mod 32 banks = 28
                            // -> consecutive rows staggered across banks (no
                            // same-bank column alignment like a 128 B stride).
#define CHUNK_FLOATS (NC*COLS*ZST)   // 3136 floats = 12.25 KB per buffer

// Fused cost-volume + mask kernel.
// block = (y, di, x-quarter); threads = (djg:3, xl:20, zg:5) = 300 active / 320.
// vs the 515-us baseline, ONE structural change: double-buffered staging with
// the async split (issue chunk cc+1's global loads BEFORE compute of chunk cc,
// ds_write them AFTER) -> 9 barriers instead of 17, staging latency hidden
// under 240 FMAs/chunk. LDS 24.5 KB keeps >=6 blocks/CU; stores stay plain
// float4 (NT stores + launch_bounds(.,4) caused the r3 regression).
// Accumulation order (c ascending, fmaf, *1/32 at end) bit-identical (absmax 0).
__global__ __launch_bounds__(320)
void fused_kernel(const float* __restrict__ f1, const float* __restrict__ a1,
                  const float* __restrict__ f2, const float* __restrict__ a2,
                  float* __restrict__ outc, float* __restrict__ outm)
{
    __shared__ __align__(16) float f2s[2][CHUNK_FLOATS];   // 25088 B
    __shared__ float m1s[XQ];
    __shared__ float m2s[COLS];

    // XCD-aware swizzle: 2880 blocks % 8 == 0 -> 360 contiguous per XCD;
    // consecutive-per-XCD blocks share y -> f1/f2 rows stay L2-local.
    int bid = blockIdx.x;
    int swz = (bid & 7) * 360 + (bid >> 3);
    int y  = swz / 36;
    int r0 = swz % 36;
    int di = r0 >> 2;       // 0..8
    int xq = r0 & 3;        // 0..3

    int t   = threadIdx.x;
    int djg = t / 100;      // 0..2 (active threads)
    int r   = t % 100;
    int xl  = r / 5;        // 0..19
    int zg  = r % 5;        // 0..4
    int z0  = zg * 4;
    int x   = xq * XQ + xl;
    int pos = y * W + x;
    int y2  = y + di - 4;
    bool y2ok = ((unsigned)y2 < (unsigned)H);
    bool act  = (t < 300);

    // staging role: threads [0,112) = NC*COLS stagers (also compute threads)
    int sc_  = t / COLS;          // channel within chunk 0..3
    int scol = t % COLS;          // halo column 0..27
    int sx2  = xq * XQ + scol - 4;
    bool stager = (t < NC * COLS) && y2ok && ((unsigned)sx2 < (unsigned)W);
    const float* sp_base = stager ? (f2 + (size_t)sc_ * NP3 + (y2 * W + sx2) * DD) : f2;
    float* sd0 = &f2s[0][0] + (sc_ * COLS + scol) * ZST + 2;   // +2: front depth pad

    // One-time zero of both buffers: covers depth pads, OOR halo columns, and
    // fully-OOR rows (y2ok == false). Staging never writes the pad area.
    for (int i = t; i < 2 * CHUNK_FLOATS / 4; i += 320)
        ((float4*)f2s)[i] = make_float4(0.f, 0.f, 0.f, 0.f);

    // visibility row-sums (same arithmetic order as the passing kernel)
    if (t < XQ){
        const float* p = a1 + (y * W + xq * XQ + t) * DD;
        float sm = 0.f;
        #pragma unroll
        for (int q = 0; q < 5; ++q){
            float4 v = *(const float4*)(p + q * 4);
            sm += v.x + v.y + v.z + v.w;
        }
        m1s[t] = fminf(fmaxf(sm, 0.f), 1.f);
    } else if (t >= 32 && t < 32 + COLS){
        int col = t - 32;
        int x2 = xq * XQ + col - 4;
        float m = 1.f;                       // spatial/row pad of mask2 is 1.0
        if (y2ok && ((unsigned)x2 < (unsigned)W)){
            const float* p = a2 + (y2 * W + x2) * DD;
            float sm = 0.f;
            #pragma unroll
            for (int q = 0; q < 5; ++q){
                float4 v = *(const float4*)(p + q * 4);
                sm += v.x + v.y + v.z + v.w;
            }
            m = fminf(fmaxf(sm, 0.f), 1.f);
        }
        m2s[col] = m;
    }
    __syncthreads();          // zero-fill + masks complete

    // prologue: stage chunk 0 into buf 0
    if (stager){
        #pragma unroll
        for (int q = 0; q < 5; ++q){
            float4 v = *(const float4*)(sp_base + q * 4);
            *(float2*)(sd0 + q * 4)     = make_float2(v.x, v.y);
            *(float2*)(sd0 + q * 4 + 2) = make_float2(v.z, v.w);
        }
    }
    __syncthreads();

    float acc[3][DO_][4];
    #pragma unroll
    for (int i = 0; i < 3; ++i)
        #pragma unroll
        for (int j = 0; j < DO_; ++j)
            #pragma unroll
            for (int k = 0; k < 4; ++k) acc[i][j][k] = 0.f;

    const float* a_base = f1 + pos * DD + z0;

    #pragma unroll 1
    for (int cc = 0; cc < NCHUNK; ++cc){
        // ---- T14 issue-early: next chunk's global loads into registers ----
        bool doStage = (cc < NCHUNK - 1) && stager;
        float4 st[5];
        if (doStage){
            const float* p = sp_base + (size_t)(cc + 1) * NC * NP3;
            #pragma unroll
            for (int q = 0; q < 5; ++q) st[q] = *(const float4*)(p + q * 4);
        }
        // ---- compute current chunk from buf[cc&1] (hides the load latency) ----
        if (act){
            const float* base = &f2s[cc & 1][0];
            #pragma unroll
            for (int c = 0; c < NC; ++c){
                float4 avv = *(const float4*)(a_base + (size_t)(cc * NC + c) * NP3);
                float av[4] = {avv.x, avv.y, avv.z, avv.w};
                #pragma unroll
                for (int djl = 0; djl < 3; ++djl){
                    int dj = djg * 3 + djl;
                    // window zs = z0 .. z0+7  <=>  zp = z0-2 .. z0+5
                    const float* bp = base + (c * COLS + xl + dj) * ZST + z0;
                    float4 b0 = *(const float4*)(bp);
                    float4 b1 = *(const float4*)(bp + 4);
                    float bb[8] = {b0.x, b0.y, b0.z, b0.w, b1.x, b1.y, b1.z, b1.w};
                    #pragma unroll
                    for (int dk = 0; dk < DO_; ++dk)
                        #pragma unroll
                        for (int z = 0; z < 4; ++z)
                            acc[djl][dk][z] = fmaf(av[z], bb[z + dk], acc[djl][dk][z]);
                }
            }
        }
        // ---- T14 write-late: park the staged chunk into the other buffer ----
        if (doStage){
            float* d = sd0 + ((cc + 1) & 1) * CHUNK_FLOATS;
            #pragma unroll
            for (int q = 0; q < 5; ++q){
                *(float2*)(d + q * 4)     = make_float2(st[q].x, st[q].y);
                *(float2*)(d + q * 4 + 2) = make_float2(st[q].z, st[q].w);
            }
        }
        if (cc < NCHUNK - 1) __syncthreads();   // buf[(cc+1)&1] ready; readers of buf[cc&1] done
    }

    if (act){
        const float sc = 1.0f / 32.0f;
        float m1v = m1s[xl];
        #pragma unroll
        for (int djl = 0; djl < 3; ++djl){
            int dj = djg * 3 + djl;
            float m2v = m2s[xl + dj];            // 1.0 when spatially OOR -> mi == m1v
            float mi = fminf(m1v * m2v, 1.f);
            #pragma unroll
            for (int dk = 0; dk < DO_; ++dk){
                size_t off = (size_t)(dk * 81 + di * 9 + dj) * NP3 + pos * DD + z0;
                float4 wv;
                wv.x = acc[djl][dk][0] * sc;
                wv.y = acc[djl][dk][1] * sc;
                wv.z = acc[djl][dk][2] * sc;
                wv.w = acc[djl][dk][3] * sc;
                *(float4*)(outc + off) = wv;
                int zlo = 2 - dk, zhi = 22 - dk;  // depth pad of mask2 = 1 -> m1v
                float4 mv;
                mv.x = (z0 + 0 >= zlo && z0 + 0 < zhi) ? mi : m1v;
                mv.y = (z0 + 1 >= zlo && z0 + 1 < zhi) ? mi : m1v;
                mv.z = (z0 + 2 >= zlo && z0 + 2 < zhi) ? mi : m1v;
                mv.w = (z0 + 3 >= zlo && z0 + 3 < zhi) ? mi : m1v;
                *(float4*)(outm + off) = mv;
            }
        }
    }
}

extern "C" void kernel_launch(void* const* d_in, const int* in_sizes, int n_in,
                              void* d_out, int out_size, void* d_ws, size_t ws_size,
                              hipStream_t stream)
{
    const float* f1 = (const float*)d_in[0];   // mpi1_features [32][80][80][20] f32
    const float* a1 = (const float*)d_in[1];   // mpi1_alpha
    const float* f2 = (const float*)d_in[2];   // mpi2_features
    const float* a2 = (const float*)d_in[3];   // mpi2_alpha
    float* outc = (float*)d_out;                   // cost volume [405][6400][20]
    float* outm = outc + (size_t)NDISP * NP3;      // mask volume, same shape
    (void)d_ws; (void)ws_size; (void)in_sizes; (void)n_in;

    fused_kernel<<<80 * SO * 4, 320, 0, stream>>>(f1, a1, f2, a2, outc, outm);
}

// Round 5
// 502.632 us; speedup vs baseline: 1.1474x; 1.1100x over previous
//
#include <hip/hip_runtime.h>

#define H 80
#define W 80
#define DD 20
#define C 32
#define NPOS (H*W)          // 6400
#define NP3 (NPOS*DD)       // 128000
#define SO 9
#define DO_ 5
#define NDISP (DO_*SO*SO)   // 405

#define NC 4                // channels staged per chunk
#define NCHUNK (C/NC)       // 8
#define XQ 20               // x-positions per block
#define COLS 28             // XQ + 8 halo columns (x2 = x-4 .. x+4+19)
#define ZST 28              // z stride: 2 front pad + 20 real + 6 back/bank pad
#define F2S_FLOATS (NC*COLS*ZST)   // 3136 floats = 12.25 KB

typedef float nt4 __attribute__((ext_vector_type(4)));   // native vec for NT stores

// EXACTLY the 515-us r1 kernel + ONE change: output stores are non-temporal
// (nt flag) so the 415 MB write stream doesn't evict the ~33 MB f1/f2 L2
// working set (f1 is logically re-read 27x; streamed outputs are never re-read).
// Everything else (single-buffered staging, 2 barriers/chunk, natural VGPR,
// 12.25 KB LDS) is untouched. Accumulation order bit-identical (absmax 0).
__global__ __launch_bounds__(320)
void fused_kernel(const float* __restrict__ f1, const float* __restrict__ a1,
                  const float* __restrict__ f2, const float* __restrict__ a2,
                  float* __restrict__ outc, float* __restrict__ outm)
{
    __shared__ __align__(16) float f2s[F2S_FLOATS];
    __shared__ float m1s[XQ];
    __shared__ float m2s[COLS];

    // XCD-aware swizzle: 2880 blocks % 8 == 0 -> 360 contiguous per XCD.
    // Consecutive-per-XCD blocks share y (36 blocks/y) -> f1/f2 rows stay L2-local.
    int bid = blockIdx.x;
    int swz = (bid & 7) * 360 + (bid >> 3);
    int y  = swz / 36;
    int r0 = swz % 36;
    int di = r0 >> 2;       // 0..8
    int xq = r0 & 3;        // 0..3

    int t   = threadIdx.x;
    int djg = t / 100;      // 0..2 (for active threads)
    int r   = t % 100;
    int xl  = r / 5;        // 0..19
    int zg  = r % 5;        // 0..4
    int z0  = zg * 4;
    int x   = xq * XQ + xl;
    int pos = y * W + x;
    int y2  = y + di - 4;
    bool y2ok = ((unsigned)y2 < (unsigned)H);
    bool act  = (t < 300);

    // One-time zero of the staging buffer: covers depth pads (zs 0,1 and 22..27),
    // out-of-range halo columns, and fully-OOR rows (y2ok == false).
    for (int i = t; i < F2S_FLOATS / 4; i += 320)
        ((float4*)f2s)[i] = make_float4(0.f, 0.f, 0.f, 0.f);

    // visibility row-sums (exact same arithmetic order as the previous kernel)
    if (t < XQ){
        const float* p = a1 + (y * W + xq * XQ + t) * DD;
        float s = 0.f;
        #pragma unroll
        for (int q = 0; q < 5; ++q){
            float4 v = *(const float4*)(p + q * 4);
            s += v.x + v.y + v.z + v.w;
        }
        m1s[t] = fminf(fmaxf(s, 0.f), 1.f);
    } else if (t >= 32 && t < 32 + COLS){
        int col = t - 32;
        int x2 = xq * XQ + col - 4;
        float m = 1.f;                       // spatial/row pad of mask2 is 1.0
        if (y2ok && ((unsigned)x2 < (unsigned)W)){
            const float* p = a2 + (y2 * W + x2) * DD;
            float s = 0.f;
            #pragma unroll
            for (int q = 0; q < 5; ++q){
                float4 v = *(const float4*)(p + q * 4);
                s += v.x + v.y + v.z + v.w;
            }
            m = fminf(fmaxf(s, 0.f), 1.f);
        }
        m2s[col] = m;
    }
    __syncthreads();

    float acc[3][DO_][4];
    #pragma unroll
    for (int i = 0; i < 3; ++i)
        #pragma unroll
        for (int j = 0; j < DO_; ++j)
            #pragma unroll
            for (int k = 0; k < 4; ++k) acc[i][j][k] = 0.f;

    const float* a_base = f1 + pos * DD + z0;

    #pragma unroll 1
    for (int cc = 0; cc < NCHUNK; ++cc){
        // ---- stage NC channels of f2 row y2 into LDS (zs = z + 2) ----
        if (y2ok && t < NC * COLS){
            int c   = t / COLS;
            int col = t % COLS;
            int x2  = xq * XQ + col - 4;
            if ((unsigned)x2 < (unsigned)W){
                const float* p = f2 + (size_t)(cc * NC + c) * NP3 + (y2 * W + x2) * DD;
                float* d = f2s + (c * COLS + col) * ZST + 2;   // +2: front depth pad
                #pragma unroll
                for (int q = 0; q < 5; ++q){
                    float4 v = *(const float4*)(p + q * 4);
                    *(float2*)(d + q * 4)     = make_float2(v.x, v.y);
                    *(float2*)(d + q * 4 + 2) = make_float2(v.z, v.w);
                }
            }
        }
        // f1 fragment for this chunk — issued BEFORE the barrier so the global
        // load latency overlaps the staging window.
        float av[NC][4];
        if (act){
            #pragma unroll
            for (int c = 0; c < NC; ++c){
                float4 v = *(const float4*)(a_base + (size_t)(cc * NC + c) * NP3);
                av[c][0] = v.x; av[c][1] = v.y; av[c][2] = v.z; av[c][3] = v.w;
            }
        }
        __syncthreads();
        if (act){
            #pragma unroll
            for (int c = 0; c < NC; ++c){
                #pragma unroll
                for (int djl = 0; djl < 3; ++djl){
                    int dj = djg * 3 + djl;
                    // window zs = z0 .. z0+7  <=>  zp = z0-2 .. z0+5 (16B aligned)
                    const float* bp = f2s + (c * COLS + xl + dj) * ZST + z0;
                    float4 b0 = *(const float4*)(bp);
                    float4 b1 = *(const float4*)(bp + 4);
                    float bb[8] = {b0.x, b0.y, b0.z, b0.w, b1.x, b1.y, b1.z, b1.w};
                    #pragma unroll
                    for (int dk = 0; dk < DO_; ++dk)
                        #pragma unroll
                        for (int z = 0; z < 4; ++z)
                            acc[djl][dk][z] = fmaf(av[c][z], bb[z + dk], acc[djl][dk][z]);
                }
            }
        }
        __syncthreads();
    }

    if (act){
        const float sc = 1.0f / 32.0f;
        float m1v = m1s[xl];
        #pragma unroll
        for (int djl = 0; djl < 3; ++djl){
            int dj = djg * 3 + djl;
            float m2v = m2s[xl + dj];            // 1.0 when spatially OOR -> mi == m1v
            float mi = fminf(m1v * m2v, 1.f);
            #pragma unroll
            for (int dk = 0; dk < DO_; ++dk){
                size_t off = (size_t)(dk * 81 + di * 9 + dj) * NP3 + pos * DD + z0;
                nt4 wv;
                wv.x = acc[djl][dk][0] * sc;
                wv.y = acc[djl][dk][1] * sc;
                wv.z = acc[djl][dk][2] * sc;
                wv.w = acc[djl][dk][3] * sc;
                __builtin_nontemporal_store(wv, (nt4*)(outc + off));
                int zlo = 2 - dk, zhi = 22 - dk;  // depth pad of mask2 = 1 -> m1v
                nt4 mv;
                mv.x = (z0 + 0 >= zlo && z0 + 0 < zhi) ? mi : m1v;
                mv.y = (z0 + 1 >= zlo && z0 + 1 < zhi) ? mi : m1v;
                mv.z = (z0 + 2 >= zlo && z0 + 2 < zhi) ? mi : m1v;
                mv.w = (z0 + 3 >= zlo && z0 + 3 < zhi) ? mi : m1v;
                __builtin_nontemporal_store(mv, (nt4*)(outm + off));
            }
        }
    }
}

extern "C" void kernel_launch(void* const* d_in, const int* in_sizes, int n_in,
                              void* d_out, int out_size, void* d_ws, size_t ws_size,
                              hipStream_t stream)
{
    const float* f1 = (const float*)d_in[0];   // mpi1_features [32][80][80][20] f32
    const float* a1 = (const float*)d_in[1];   // mpi1_alpha
    const float* f2 = (const float*)d_in[2];   // mpi2_features
    const float* a2 = (const float*)d_in[3];   // mpi2_alpha
    float* outc = (float*)d_out;                   // cost volume [405][6400][20]
    float* outm = outc + (size_t)NDISP * NP3;      // mask volume, same shape
    (void)d_ws; (void)ws_size; (void)in_sizes; (void)n_in;

    fused_kernel<<<80 * SO * 4, 320, 0, stream>>>(f1, a1, f2, a2, outc, outm);
}